// Round 29
// baseline (331.843 us; speedup 1.0000x reference)
//
#include <hip/hip_runtime.h>

// Round 29: counted-vmcnt 8-phase for QK/PV — R24 geometry (256x256, 8 waves,
// 2x64KB dbuf; bit-exact-validated) with the m218 fix: staging reordered to
// consumption order (B first, A split by phase-group) so waits are COUNTED,
// never drain-0 mid-loop. Ledger (2 loads/stage-op, 8/tile, order B0,B1,A1,A2):
//   boundary: outstanding 8 -> vmcnt(2): B+A1 resident (tile-start B-frag
//             reads + phases 0-1 A-reads covered), A2 still in flight
//   pre-phase2: outstanding A2(t)*2 + B(t+1)*4 = 6 -> vmcnt(4) retires A2
//   (last tile: vmcnt(0))
// Each wait + s_barrier -> cross-wave LDS visibility. prep/proj_split/softmax
// identical to R28 (315us best).

typedef __attribute__((ext_vector_type(8))) _Float16 f16x8;
typedef __attribute__((ext_vector_type(4))) float f32x4;
typedef unsigned short u16;
typedef unsigned int u32;

#define B_ 8
#define SQL 2048
#define SKL 2048
#define DD 1024
#define NEGC -1000000000.0f

static __device__ __forceinline__ u16 f2h(float x) {
  _Float16 h = (_Float16)x;                       // v_cvt_f16_f32, RNE
  return __builtin_bit_cast(u16, h);
}
static __device__ __forceinline__ float h2f(u16 v) {
  return (float)__builtin_bit_cast(_Float16, v);
}
static __device__ __forceinline__ void gload16(const void* g, void* l) {
  __builtin_amdgcn_global_load_lds((const __attribute__((address_space(1))) u32*)g,
                                   (__attribute__((address_space(3))) u32*)l, 16, 0, 0);
}

// ---------------- fused1: cvt16(query) [blocks 0..2047] + split16(W) [2048..2559] ----------------
__global__ __launch_bounds__(256) void prep_k(const float* __restrict__ query,
                                              u16* __restrict__ q16,
                                              const float* __restrict__ Wm,
                                              u16* __restrict__ wh, u16* __restrict__ wl) {
  if (blockIdx.x < 2048) {
    long n = (long)B_ * SQL * DD;
    long i = ((long)blockIdx.x * 256 + threadIdx.x) * 8;
    long stride = 2048L * 256 * 8;
    for (; i < n; i += stride) {
      float4 v0 = *(const float4*)(query + i);
      float4 v1 = *(const float4*)(query + i + 4);
      ushort4 o0 = make_ushort4(f2h(v0.x), f2h(v0.y), f2h(v0.z), f2h(v0.w));
      ushort4 o1 = make_ushort4(f2h(v1.x), f2h(v1.y), f2h(v1.z), f2h(v1.w));
      *(ushort4*)(q16 + i) = o0;
      *(ushort4*)(q16 + i + 4) = o1;
    }
  } else {
    long i = ((long)(blockIdx.x - 2048) * 256 + threadIdx.x) * 8;   // W: 1M elems
    float4 v0 = *(const float4*)(Wm + i);
    float4 v1 = *(const float4*)(Wm + i + 4);
    u16 h0 = f2h(v0.x), h1 = f2h(v0.y), h2 = f2h(v0.z), h3 = f2h(v0.w);
    u16 h4 = f2h(v1.x), h5 = f2h(v1.y), h6 = f2h(v1.z), h7 = f2h(v1.w);
    *(ushort4*)(wh + i) = make_ushort4(h0, h1, h2, h3);
    *(ushort4*)(wh + i + 4) = make_ushort4(h4, h5, h6, h7);
    *(ushort4*)(wl + i) = make_ushort4(f2h(v0.x - h2f(h0)), f2h(v0.y - h2f(h1)),
                                       f2h(v0.z - h2f(h2)), f2h(v0.w - h2f(h3)));
    *(ushort4*)(wl + i + 4) = make_ushort4(f2h(v1.x - h2f(h4)), f2h(v1.y - h2f(h5)),
                                           f2h(v1.z - h2f(h6)), f2h(v1.w - h2f(h7)));
  }
}

// ---------------- fused2: proj (256x128, TERMS=2) + split_mem (back-to-back) ----------------
__global__ __launch_bounds__(256, 2) void proj_split_k(
    const u16* __restrict__ Ah, const u16* __restrict__ Bh, const u16* __restrict__ Bl,
    const float* __restrict__ bias, u16* __restrict__ C0,
    const float* __restrict__ mem, u16* __restrict__ memh, u16* __restrict__ memT) {
  __shared__ u16 lA[256 * 64];     // 32KB
  __shared__ u16 lB[128 * 128];    // 32KB

  if (blockIdx.x < 512) {
    const int N = DD, K = DD;
    int id = blockIdx.x;
    int j = (id & 7) * 64 + (id >> 3);      // bijective, nwg=512
    const int TX = N >> 7;                  // 8
    const int by = j / TX, bx = j % TX;
    const int tid = threadIdx.x;
    const int l = tid & 63, w = tid >> 6;
    const int wr = w >> 1, wc = w & 1;
    const long am0 = (long)by * 256;
    const long bn0 = (long)bx * 128;

    f32x4 acc[8][4];
#pragma unroll
    for (int i = 0; i < 8; ++i)
#pragma unroll
      for (int j2 = 0; j2 < 4; ++j2) {
        f32x4 z = {0.f, 0.f, 0.f, 0.f};
        acc[i][j2] = z;
      }
    const int lrow = l & 15, lch = l >> 4;

    for (int k0 = 0; k0 < K; k0 += 64) {
      __syncthreads();
#pragma unroll
      for (int i = 0; i < 8; ++i) {
        int row = i * 32 + (tid >> 3);
        int cc = (tid & 7) ^ (row & 7);
        gload16(Ah + (am0 + row) * K + k0 + cc * 8, &lA[row * 64 + (tid & 7) * 8]);
      }
#pragma unroll
      for (int i = 0; i < 8; ++i) {
        int row = i * 16 + (tid >> 4);
        int s = tid & 15;
        int cc = s ^ (row & 15);
        const u16* src = (cc < 8) ? (Bh + (bn0 + row) * K + k0 + cc * 8)
                                  : (Bl + (bn0 + row) * K + k0 + (cc - 8) * 8);
        gload16(src, &lB[row * 128 + s * 8]);
      }
      __syncthreads();

#pragma unroll
      for (int kk = 0; kk < 2; ++kk) {
        f16x8 ah[8], bh[4], bl_[4];
#pragma unroll
        for (int f = 0; f < 8; ++f) {
          int ra = wr * 128 + f * 16 + lrow;
          int c = kk * 4 + lch;
          ah[f] = *(const f16x8*)&lA[ra * 64 + (c ^ (ra & 7)) * 8];
        }
#pragma unroll
        for (int f = 0; f < 4; ++f) {
          int rb = wc * 64 + f * 16 + lrow;
          int c = kk * 4 + lch;
          bh[f] = *(const f16x8*)&lB[rb * 128 + (c ^ (rb & 15)) * 8];
          bl_[f] = *(const f16x8*)&lB[rb * 128 + ((8 + c) ^ (rb & 15)) * 8];
        }
#pragma unroll
        for (int mf = 0; mf < 8; ++mf)
#pragma unroll
          for (int nf = 0; nf < 4; ++nf) {
            acc[mf][nf] = __builtin_amdgcn_mfma_f32_16x16x32_f16(ah[mf], bh[nf], acc[mf][nf], 0, 0, 0);
            acc[mf][nf] = __builtin_amdgcn_mfma_f32_16x16x32_f16(ah[mf], bl_[nf], acc[mf][nf], 0, 0, 0);
          }
      }
    }
#pragma unroll
    for (int mf = 0; mf < 8; ++mf)
#pragma unroll
      for (int nf = 0; nf < 4; ++nf)
#pragma unroll
        for (int r = 0; r < 4; ++r) {
          long row = am0 + wr * 128 + mf * 16 + (l >> 4) * 4 + r;
          long col = bn0 + wc * 64 + nf * 16 + (l & 15);
          C0[row * N + col] = f2h(acc[mf][nf][r] + bias[col]);
        }
  } else {
    u16(*t)[65] = (u16(*)[65])lA;   // 8.3KB alias
    int id2 = blockIdx.x - 512;
    int bx = id2 & 15, by = (id2 >> 4) & 31, bz = id2 >> 9;
    long bo = (long)bz * SKL * DD;
    int r0 = by * 64, c0 = bx * 64;
    int tr = threadIdx.x / 16, tc4 = (threadIdx.x % 16) * 4;
#pragma unroll
    for (int i = 0; i < 4; ++i) {
      int r = tr + i * 16;
      long idx = bo + (long)(r0 + r) * DD + c0 + tc4;
      float4 v = *(const float4*)(mem + idx);
      u16 h0 = f2h(v.x), h1 = f2h(v.y), h2 = f2h(v.z), h3 = f2h(v.w);
      *(ushort4*)(memh + idx) = make_ushort4(h0, h1, h2, h3);
      t[r][tc4 + 0] = h0; t[r][tc4 + 1] = h1; t[r][tc4 + 2] = h2; t[r][tc4 + 3] = h3;
    }
    __syncthreads();
#pragma unroll
    for (int i = 0; i < 4; ++i) {
      int c = tr + i * 16;
      ushort4 v = make_ushort4(t[tc4 + 0][c], t[tc4 + 1][c], t[tc4 + 2][c], t[tc4 + 3][c]);
      *(ushort4*)(memT + bo + (long)(c0 + c) * SKL + r0 + tc4) = v;
    }
  }
}

// ---------------- counted 8-phase TERMS=1 GEMM (QK / PV) ----------------
// 256x256, 8 waves (2x4), BK=64, 2x64KB LDS dbuf.
// Stage order per tile: S_B0(B rows 0-127), S_B1(128-255),
//   S_A1(A rows 0-63 & 128-191), S_A2(64-127 & 192-255)  -- consumption order.
template <int OUTMODE>
__global__ __launch_bounds__(512, 2) void gemm8p_f16(
    const u16* __restrict__ Ah, const u16* __restrict__ Bh,
    void* __restrict__ C0,
    int N, int K, int TPB, long batchA, long batchB, long batchC) {
  __shared__ u16 lA[2][256 * 64];   // 64KB
  __shared__ u16 lB[2][256 * 64];   // 64KB

  const int nwg = gridDim.x;
  int id = blockIdx.x;
  int j = (id & 7) * (nwg >> 3) + (id >> 3);
  const int TX = N >> 8;            // N/256
  const int bz = j / TPB;
  const int r0_ = j % TPB;
  const int by = r0_ / TX, bx = r0_ % TX;

  const u16* pA = Ah + (long)bz * batchA;
  const u16* pB = Bh + (long)bz * batchB;

  const int tid = threadIdx.x;
  const int l = tid & 63, w = tid >> 6;
  const int wr = w >> 2, wc = w & 3;          // 2 x 4 waves
  const long am0 = (long)by * 256;
  const long bn0 = (long)bx * 256;
  const int lrow = l & 15, lch = l >> 4;
  const int srow = tid >> 3, schunk = tid & 7;   // 64 rows x 8 chunks per load-op

  f32x4 acc[8][4];
#pragma unroll
  for (int i = 0; i < 8; ++i)
#pragma unroll
    for (int j2 = 0; j2 < 4; ++j2) {
      f32x4 z = {0.f, 0.f, 0.f, 0.f};
      acc[i][j2] = z;
    }

  // one 64-row load-op (1 gload16/thread = 1 vmcnt unit)
  auto LD64 = [&](const u16* p, long b0, u16* dst, int rbase, int k0) {
    int row = rbase + srow;
    int cc = schunk ^ (row & 7);
    gload16(p + (b0 + row) * K + k0 + cc * 8, dst + row * 64 + schunk * 8);
  };

  // prologue: tile 0, order B0,B1,A1,A2 (8 vmcnt units in flight)
  {
    u16* dA = &lA[0][0];
    u16* dB = &lB[0][0];
    LD64(pB, bn0, dB, 0, 0);   LD64(pB, bn0, dB, 64, 0);     // S_B0
    LD64(pB, bn0, dB, 128, 0); LD64(pB, bn0, dB, 192, 0);    // S_B1
    LD64(pA, am0, dA, 0, 0);   LD64(pA, am0, dA, 128, 0);    // S_A1
    LD64(pA, am0, dA, 64, 0);  LD64(pA, am0, dA, 192, 0);    // S_A2
  }

  const int KITER = K >> 6;
  for (int t = 0; t < KITER; ++t) {
    const int c = t & 1;
    const int k1 = (t + 1) << 6;
    const bool more = (t + 1 < KITER);
    u16* dA = &lA[c ^ 1][0];
    u16* dB = &lB[c ^ 1][0];

    // boundary: B(t)+A1(t) resident (6 oldest of 8); A2(t) may still fly
    asm volatile("s_waitcnt vmcnt(2)" ::: "memory");
    __builtin_amdgcn_sched_barrier(0);
    __builtin_amdgcn_s_barrier();

    // B-frags for the whole tile (8 ds_read_b128), held in regs
    f16x8 bfr[4][2];
#pragma unroll
    for (int nf = 0; nf < 4; ++nf)
#pragma unroll
      for (int kk = 0; kk < 2; ++kk) {
        int rb = wc * 64 + nf * 16 + lrow;
        int cch = kk * 4 + lch;
        bfr[nf][kk] = *(const f16x8*)&lB[c][rb * 64 + (cch ^ (rb & 7)) * 8];
      }

#pragma unroll
    for (int p = 0; p < 4; ++p) {
      if (p == 2) {
        // A2(t) must be resident: outstanding = A2(t)*2 [+ B(t+1)*4 if more]
        if (more) asm volatile("s_waitcnt vmcnt(4)" ::: "memory");
        else      asm volatile("s_waitcnt vmcnt(0)" ::: "memory");
        __builtin_amdgcn_sched_barrier(0);
        __builtin_amdgcn_s_barrier();
      }
      // ds_read this quadrant's A-frags
      f16x8 afr[2][2];
#pragma unroll
      for (int mi = 0; mi < 2; ++mi)
#pragma unroll
        for (int kk = 0; kk < 2; ++kk) {
          int ra = wr * 128 + (2 * p + mi) * 16 + lrow;
          int cch = kk * 4 + lch;
          afr[mi][kk] = *(const f16x8*)&lA[c][ra * 64 + (cch ^ (ra & 7)) * 8];
        }
      // stage for tile t+1 (consumption order)
      if (more) {
        if (p == 0)      { LD64(pB, bn0, dB, 0, k1);   LD64(pB, bn0, dB, 64, k1); }
        else if (p == 1) { LD64(pB, bn0, dB, 128, k1); LD64(pB, bn0, dB, 192, k1); }
        else if (p == 2) { LD64(pA, am0, dA, 0, k1);   LD64(pA, am0, dA, 128, k1); }
        else             { LD64(pA, am0, dA, 64, k1);  LD64(pA, am0, dA, 192, k1); }
      }
      __builtin_amdgcn_s_barrier();
      __builtin_amdgcn_s_setprio(1);
#pragma unroll
      for (int kk = 0; kk < 2; ++kk)
#pragma unroll
        for (int mi = 0; mi < 2; ++mi)
#pragma unroll
          for (int nf = 0; nf < 4; ++nf)
            acc[2 * p + mi][nf] = __builtin_amdgcn_mfma_f32_16x16x32_f16(
                afr[mi][kk], bfr[nf][kk], acc[2 * p + mi][nf], 0, 0, 0);
      __builtin_amdgcn_s_setprio(0);
      __builtin_amdgcn_s_barrier();
    }
  }

  // epilogue: C/D layout col = lane&15, row = (lane>>4)*4 + reg
#pragma unroll
  for (int mf = 0; mf < 8; ++mf)
#pragma unroll
    for (int nf = 0; nf < 4; ++nf)
#pragma unroll
      for (int r = 0; r < 4; ++r) {
        long row = am0 + wr * 128 + mf * 16 + (l >> 4) * 4 + r;
        long col = bn0 + wc * 64 + nf * 16 + (l & 15);
        long idx = (long)bz * batchC + row * N + col;
        if (OUTMODE == 0) ((float*)C0)[idx] = acc[mf][nf][r];
        else              ((u16*)C0)[idx] = f2h(acc[mf][nf][r]);
      }
}

// ---------------- mask + row softmax, wave-per-row (no barriers/LDS) ----------------
__global__ __launch_bounds__(256) void softmax16_k(const float* __restrict__ S,
                                                   const int* __restrict__ M,
                                                   u16* __restrict__ P) {
  long row = (long)blockIdx.x * 4 + (threadIdx.x >> 6);
  const float* s = S + row * SKL;
  const int* m = M + row * SKL;
  u16* p = P + row * SKL;
  const int lane = threadIdx.x & 63;
  float x[32];
#pragma unroll
  for (int j = 0; j < 8; ++j) {
    float4 v = *(const float4*)(s + lane * 4 + j * 256);
    int4 q = *(const int4*)(m + lane * 4 + j * 256);
    x[j * 4 + 0] = q.x ? v.x : v.x + NEGC;
    x[j * 4 + 1] = q.y ? v.y : v.y + NEGC;
    x[j * 4 + 2] = q.z ? v.z : v.z + NEGC;
    x[j * 4 + 3] = q.w ? v.w : v.w + NEGC;
  }
  float mx = x[0];
#pragma unroll
  for (int j = 1; j < 32; ++j) mx = fmaxf(mx, x[j]);
#pragma unroll
  for (int o = 32; o >= 1; o >>= 1) mx = fmaxf(mx, __shfl_xor(mx, o, 64));
  float sum = 0.f;
#pragma unroll
  for (int j = 0; j < 32; ++j) { x[j] = __expf(x[j] - mx); sum += x[j]; }
#pragma unroll
  for (int o = 32; o >= 1; o >>= 1) sum += __shfl_xor(sum, o, 64);
  float inv = 1.f / sum;
#pragma unroll
  for (int j = 0; j < 8; ++j) {
    ushort4 o4 = make_ushort4(f2h(x[j * 4 + 0] * inv), f2h(x[j * 4 + 1] * inv),
                              f2h(x[j * 4 + 2] * inv), f2h(x[j * 4 + 3] * inv));
    *(ushort4*)(p + lane * 4 + j * 256) = o4;
  }
}

extern "C" void kernel_launch(void* const* d_in, const int* in_sizes, int n_in,
                              void* d_out, int out_size, void* d_ws, size_t ws_size,
                              hipStream_t stream) {
  const float* query = (const float*)d_in[0];
  const float* mem = (const float*)d_in[1];
  const int* mask = (const int*)d_in[2];
  const float* Wm = (const float*)d_in[3];
  const float* bias = (const float*)d_in[4];
  float* out = (float*)d_out;   // fp32 output

  const long nQ = (long)B_ * SQL * DD;   // 16.7M
  const long nW = (long)DD * DD;
  const long nS = (long)B_ * SQL * SKL;

  char* ws = (char*)d_ws;
  u16* q16 = (u16*)ws; ws += nQ * 2;    // fp16(query); becomes P after proj+QK
  u16* memh = (u16*)ws; ws += nQ * 2;
  u16* memT = (u16*)ws; ws += nQ * 2;
  u16* q1 = (u16*)ws; ws += nQ * 2;     // projected q, fp16
  u16* wh = (u16*)ws; ws += nW * 2;
  u16* wl = (u16*)ws; ws += nW * 2;
  float* S = (float*)ws; ws += nS * 4;
  u16* P = q16;   // q16 dead after projection

  // fused1: cvt16(query) + split16(W)
  prep_k<<<2048 + 512, 256, 0, stream>>>(query, q16, Wm, wh, wl);
  // fused2: proj (blocks 0-511) + split_mem (blocks 512-4607), back-to-back
  proj_split_k<<<512 + 4096, 256, 0, stream>>>(q16, wh, wl, bias, q1, mem, memh, memT);
  // logits (counted 8-phase, 256x256): per batch 8x8 -> grid 512
  gemm8p_f16<0><<<512, 512, 0, stream>>>(
      q1, memh, S, SKL, DD, 64,
      (long)SQL * DD, (long)SKL * DD, (long)SQL * SKL);
  // mask + softmax -> P fp16 (wave-per-row)
  softmax16_k<<<(B_ * SQL) / 4, 256, 0, stream>>>(S, mask, P);
  // PV (counted 8-phase, 256x256): per batch 8x4 -> grid 256
  gemm8p_f16<0><<<256, 512, 0, stream>>>(
      P, memT, out, DD, SKL, 32,
      (long)SQL * SKL, (long)DD * SKL, (long)SQL * DD);
}

// Round 30
// 315.421 us; speedup vs baseline: 1.0521x; 1.0521x over previous
//
#include <hip/hip_runtime.h>

// FINAL (round 30): the triple-reproduced best configuration
// (R23/R25/R26/R28: 314.7/315.1/315.9us, absmax 0.0742 vs threshold 0.108).
// 11.5x over the correct naive fp32 baseline (3637us).
//
// Pipeline: q=query@W^T+b ; S=q@mem^T ; P=softmax(S+mask) ; out=P@mem
//  - prep_k:        fused fp32->fp16 convert(query) + hi/lo split(W)  [BW ceiling]
//  - proj_split_k:  proj 256x128 2-term fp16 (q16 x (Wh+Wl), fp32 acc)
//                   grid-fused back-to-back with mem split+transpose  [93us]
//  - gemm1_f16:     QK & PV, 1-term fp16, 256x128 tile, 4 waves, BK=64,
//                   XOR-swizzled LDS via pre-swizzled global source
//                   (global_load_lds dest linear, rule #21), batch-folded
//                   bijective XCD-chunk swizzle (FETCH at ideal)      [92/73us]
//  - softmax16_k:   wave-per-row, shfl-only, no LDS/barriers          [BW ceiling]
//
// Measured-null/negative at this structure (4 attempts): coarse dbuf (R10),
// depth-1 counted vmcnt (R18), 8-phase drain-0 (R24), 8-phase counted (R29)
// -- barrier cost x wave count dominates; the m201-class schedule needs its
// full co-designed body, not just the sync skeleton.
// Error budget: fp16 inputs + 1-term QK/PV + 2-term proj -> logit sigma ~1e-2,
// absmax 0.074 (1.46x margin). S stays fp32 (fp16 S would be ~0.10, too tight).

typedef __attribute__((ext_vector_type(8))) _Float16 f16x8;
typedef __attribute__((ext_vector_type(4))) float f32x4;
typedef unsigned short u16;
typedef unsigned int u32;

#define B_ 8
#define SQL 2048
#define SKL 2048
#define DD 1024
#define NEGC -1000000000.0f

static __device__ __forceinline__ u16 f2h(float x) {
  _Float16 h = (_Float16)x;                       // v_cvt_f16_f32, RNE
  return __builtin_bit_cast(u16, h);
}
static __device__ __forceinline__ float h2f(u16 v) {
  return (float)__builtin_bit_cast(_Float16, v);
}
static __device__ __forceinline__ void gload16(const void* g, void* l) {
  __builtin_amdgcn_global_load_lds((const __attribute__((address_space(1))) u32*)g,
                                   (__attribute__((address_space(3))) u32*)l, 16, 0, 0);
}

// ---------------- fused1: cvt16(query) [blocks 0..2047] + split16(W) [2048..2559] ----------------
__global__ __launch_bounds__(256) void prep_k(const float* __restrict__ query,
                                              u16* __restrict__ q16,
                                              const float* __restrict__ Wm,
                                              u16* __restrict__ wh, u16* __restrict__ wl) {
  if (blockIdx.x < 2048) {
    long n = (long)B_ * SQL * DD;
    long i = ((long)blockIdx.x * 256 + threadIdx.x) * 8;
    long stride = 2048L * 256 * 8;
    for (; i < n; i += stride) {
      float4 v0 = *(const float4*)(query + i);
      float4 v1 = *(const float4*)(query + i + 4);
      ushort4 o0 = make_ushort4(f2h(v0.x), f2h(v0.y), f2h(v0.z), f2h(v0.w));
      ushort4 o1 = make_ushort4(f2h(v1.x), f2h(v1.y), f2h(v1.z), f2h(v1.w));
      *(ushort4*)(q16 + i) = o0;
      *(ushort4*)(q16 + i + 4) = o1;
    }
  } else {
    long i = ((long)(blockIdx.x - 2048) * 256 + threadIdx.x) * 8;   // W: 1M elems
    float4 v0 = *(const float4*)(Wm + i);
    float4 v1 = *(const float4*)(Wm + i + 4);
    u16 h0 = f2h(v0.x), h1 = f2h(v0.y), h2 = f2h(v0.z), h3 = f2h(v0.w);
    u16 h4 = f2h(v1.x), h5 = f2h(v1.y), h6 = f2h(v1.z), h7 = f2h(v1.w);
    *(ushort4*)(wh + i) = make_ushort4(h0, h1, h2, h3);
    *(ushort4*)(wh + i + 4) = make_ushort4(h4, h5, h6, h7);
    *(ushort4*)(wl + i) = make_ushort4(f2h(v0.x - h2f(h0)), f2h(v0.y - h2f(h1)),
                                       f2h(v0.z - h2f(h2)), f2h(v0.w - h2f(h3)));
    *(ushort4*)(wl + i + 4) = make_ushort4(f2h(v1.x - h2f(h4)), f2h(v1.y - h2f(h5)),
                                           f2h(v1.z - h2f(h6)), f2h(v1.w - h2f(h7)));
  }
}

// ---------------- fused2: proj (256x128, TERMS=2) + split_mem (back-to-back) ----------------
// blocks [0,512): projection q16 @ (Wh+Wl)^T + bias -> q1 fp16
// blocks [512,4608): mem fp32 -> memh fp16 + memT fp16 [D][Sk]  (64x64 tiles)
__global__ __launch_bounds__(256, 2) void proj_split_k(
    const u16* __restrict__ Ah, const u16* __restrict__ Bh, const u16* __restrict__ Bl,
    const float* __restrict__ bias, u16* __restrict__ C0,
    const float* __restrict__ mem, u16* __restrict__ memh, u16* __restrict__ memT) {
  __shared__ u16 lA[256 * 64];     // 32KB (proj A; split_mem aliases 8.3KB of it)
  __shared__ u16 lB[128 * 128];    // 32KB (proj B dual)

  if (blockIdx.x < 512) {
    // ---- projection: TERMS=2 path, nwg=512 swizzle ----
    const int N = DD, K = DD;
    int id = blockIdx.x;
    int j = (id & 7) * 64 + (id >> 3);      // bijective, nwg=512
    const int TX = N >> 7;                  // 8
    const int by = j / TX, bx = j % TX;
    const int tid = threadIdx.x;
    const int l = tid & 63, w = tid >> 6;
    const int wr = w >> 1, wc = w & 1;
    const long am0 = (long)by * 256;
    const long bn0 = (long)bx * 128;

    f32x4 acc[8][4];
#pragma unroll
    for (int i = 0; i < 8; ++i)
#pragma unroll
      for (int j2 = 0; j2 < 4; ++j2) {
        f32x4 z = {0.f, 0.f, 0.f, 0.f};
        acc[i][j2] = z;
      }
    const int lrow = l & 15, lch = l >> 4;

    for (int k0 = 0; k0 < K; k0 += 64) {
      __syncthreads();
#pragma unroll
      for (int i = 0; i < 8; ++i) {
        int row = i * 32 + (tid >> 3);
        int cc = (tid & 7) ^ (row & 7);
        gload16(Ah + (am0 + row) * K + k0 + cc * 8, &lA[row * 64 + (tid & 7) * 8]);
      }
#pragma unroll
      for (int i = 0; i < 8; ++i) {
        int row = i * 16 + (tid >> 4);
        int s = tid & 15;
        int cc = s ^ (row & 15);
        const u16* src = (cc < 8) ? (Bh + (bn0 + row) * K + k0 + cc * 8)
                                  : (Bl + (bn0 + row) * K + k0 + (cc - 8) * 8);
        gload16(src, &lB[row * 128 + s * 8]);
      }
      __syncthreads();

#pragma unroll
      for (int kk = 0; kk < 2; ++kk) {
        f16x8 ah[8], bh[4], bl_[4];
#pragma unroll
        for (int f = 0; f < 8; ++f) {
          int ra = wr * 128 + f * 16 + lrow;
          int c = kk * 4 + lch;
          ah[f] = *(const f16x8*)&lA[ra * 64 + (c ^ (ra & 7)) * 8];
        }
#pragma unroll
        for (int f = 0; f < 4; ++f) {
          int rb = wc * 64 + f * 16 + lrow;
          int c = kk * 4 + lch;
          bh[f] = *(const f16x8*)&lB[rb * 128 + (c ^ (rb & 15)) * 8];
          bl_[f] = *(const f16x8*)&lB[rb * 128 + ((8 + c) ^ (rb & 15)) * 8];
        }
#pragma unroll
        for (int mf = 0; mf < 8; ++mf)
#pragma unroll
          for (int nf = 0; nf < 4; ++nf) {
            acc[mf][nf] = __builtin_amdgcn_mfma_f32_16x16x32_f16(ah[mf], bh[nf], acc[mf][nf], 0, 0, 0);
            acc[mf][nf] = __builtin_amdgcn_mfma_f32_16x16x32_f16(ah[mf], bl_[nf], acc[mf][nf], 0, 0, 0);
          }
      }
    }
#pragma unroll
    for (int mf = 0; mf < 8; ++mf)
#pragma unroll
      for (int nf = 0; nf < 4; ++nf)
#pragma unroll
        for (int r = 0; r < 4; ++r) {
          long row = am0 + wr * 128 + mf * 16 + (l >> 4) * 4 + r;
          long col = bn0 + wc * 64 + nf * 16 + (l & 15);
          C0[row * N + col] = f2h(acc[mf][nf][r] + bias[col]);
        }
  } else {
    // ---- split_mem: 64x64 transpose tiles, flattened grid (16,32,8) ----
    u16(*t)[65] = (u16(*)[65])lA;   // 64x65 u16 = 8.3KB, aliases lA
    int id2 = blockIdx.x - 512;
    int bx = id2 & 15, by = (id2 >> 4) & 31, bz = id2 >> 9;
    long bo = (long)bz * SKL * DD;
    int r0 = by * 64, c0 = bx * 64;
    int tr = threadIdx.x / 16, tc4 = (threadIdx.x % 16) * 4;
#pragma unroll
    for (int i = 0; i < 4; ++i) {
      int r = tr + i * 16;
      long idx = bo + (long)(r0 + r) * DD + c0 + tc4;
      float4 v = *(const float4*)(mem + idx);
      u16 h0 = f2h(v.x), h1 = f2h(v.y), h2 = f2h(v.z), h3 = f2h(v.w);
      *(ushort4*)(memh + idx) = make_ushort4(h0, h1, h2, h3);
      t[r][tc4 + 0] = h0; t[r][tc4 + 1] = h1; t[r][tc4 + 2] = h2; t[r][tc4 + 3] = h3;
    }
    __syncthreads();
#pragma unroll
    for (int i = 0; i < 4; ++i) {
      int c = tr + i * 16;   // output row = original column c0+c
      ushort4 v = make_ushort4(t[tc4 + 0][c], t[tc4 + 1][c], t[tc4 + 2][c], t[tc4 + 3][c]);
      *(ushort4*)(memT + bo + (long)(c0 + c) * SKL + r0 + tc4) = v;
    }
  }
}

// ---------------- TERMS=1 GEMM (QK / PV): 256x128, 4 waves, BK=64 ----------------
template <int OUTMODE>
__global__ __launch_bounds__(256, 2) void gemm1_f16(
    const u16* __restrict__ Ah, const u16* __restrict__ Bh,
    void* __restrict__ C0,
    int N, int K, int TPB, long batchA, long batchB, long batchC) {
  __shared__ u16 lA[256 * 64];
  __shared__ u16 lB[128 * 64];

  const int nwg = gridDim.x;
  int id = blockIdx.x;
  int j = (id & 7) * (nwg >> 3) + (id >> 3);
  const int TX = N >> 7;
  const int bz = j / TPB;
  const int r0_ = j % TPB;
  const int by = r0_ / TX, bx = r0_ % TX;

  const u16* pAh = Ah + (long)bz * batchA;
  const u16* pBh = Bh + (long)bz * batchB;

  const int tid = threadIdx.x;
  const int l = tid & 63, w = tid >> 6;
  const int wr = w >> 1, wc = w & 1;
  const long am0 = (long)by * 256;
  const long bn0 = (long)bx * 128;

  f32x4 acc[8][4];
#pragma unroll
  for (int i = 0; i < 8; ++i)
#pragma unroll
    for (int j2 = 0; j2 < 4; ++j2) {
      f32x4 z = {0.f, 0.f, 0.f, 0.f};
      acc[i][j2] = z;
    }
  const int lrow = l & 15, lch = l >> 4;

  for (int k0 = 0; k0 < K; k0 += 64) {
    __syncthreads();
#pragma unroll
    for (int i = 0; i < 8; ++i) {
      int row = i * 32 + (tid >> 3);
      int cc = (tid & 7) ^ (row & 7);
      gload16(pAh + (am0 + row) * K + k0 + cc * 8, &lA[row * 64 + (tid & 7) * 8]);
    }
#pragma unroll
    for (int i = 0; i < 4; ++i) {
      int row = i * 32 + (tid >> 3);
      int cc = (tid & 7) ^ (row & 7);
      gload16(pBh + (bn0 + row) * K + k0 + cc * 8, &lB[row * 64 + (tid & 7) * 8]);
    }
    __syncthreads();

#pragma unroll
    for (int kk = 0; kk < 2; ++kk) {
      f16x8 ah[8], bh[4];
#pragma unroll
      for (int f = 0; f < 8; ++f) {
        int ra = wr * 128 + f * 16 + lrow;
        int c = kk * 4 + lch;
        ah[f] = *(const f16x8*)&lA[ra * 64 + (c ^ (ra & 7)) * 8];
      }
#pragma unroll
      for (int f = 0; f < 4; ++f) {
        int rb = wc * 64 + f * 16 + lrow;
        int c = kk * 4 + lch;
        bh[f] = *(const f16x8*)&lB[rb * 64 + (c ^ (rb & 7)) * 8];
      }
#pragma unroll
      for (int mf = 0; mf < 8; ++mf)
#pragma unroll
        for (int nf = 0; nf < 4; ++nf)
          acc[mf][nf] = __builtin_amdgcn_mfma_f32_16x16x32_f16(ah[mf], bh[nf], acc[mf][nf], 0, 0, 0);
    }
  }

#pragma unroll
  for (int mf = 0; mf < 8; ++mf)
#pragma unroll
    for (int nf = 0; nf < 4; ++nf)
#pragma unroll
      for (int r = 0; r < 4; ++r) {
        long row = am0 + wr * 128 + mf * 16 + (l >> 4) * 4 + r;
        long col = bn0 + wc * 64 + nf * 16 + (l & 15);
        long idx = (long)bz * batchC + row * N + col;
        if (OUTMODE == 0) ((float*)C0)[idx] = acc[mf][nf][r];
        else              ((u16*)C0)[idx] = f2h(acc[mf][nf][r]);
      }
}

// ---------------- mask + row softmax, wave-per-row (no barriers/LDS) ----------------
__global__ __launch_bounds__(256) void softmax16_k(const float* __restrict__ S,
                                                   const int* __restrict__ M,
                                                   u16* __restrict__ P) {
  long row = (long)blockIdx.x * 4 + (threadIdx.x >> 6);
  const float* s = S + row * SKL;
  const int* m = M + row * SKL;
  u16* p = P + row * SKL;
  const int lane = threadIdx.x & 63;
  float x[32];
#pragma unroll
  for (int j = 0; j < 8; ++j) {
    float4 v = *(const float4*)(s + lane * 4 + j * 256);
    int4 q = *(const int4*)(m + lane * 4 + j * 256);
    x[j * 4 + 0] = q.x ? v.x : v.x + NEGC;
    x[j * 4 + 1] = q.y ? v.y : v.y + NEGC;
    x[j * 4 + 2] = q.z ? v.z : v.z + NEGC;
    x[j * 4 + 3] = q.w ? v.w : v.w + NEGC;
  }
  float mx = x[0];
#pragma unroll
  for (int j = 1; j < 32; ++j) mx = fmaxf(mx, x[j]);
#pragma unroll
  for (int o = 32; o >= 1; o >>= 1) mx = fmaxf(mx, __shfl_xor(mx, o, 64));
  float sum = 0.f;
#pragma unroll
  for (int j = 0; j < 32; ++j) { x[j] = __expf(x[j] - mx); sum += x[j]; }
#pragma unroll
  for (int o = 32; o >= 1; o >>= 1) sum += __shfl_xor(sum, o, 64);
  float inv = 1.f / sum;
#pragma unroll
  for (int j = 0; j < 8; ++j) {
    ushort4 o4 = make_ushort4(f2h(x[j * 4 + 0] * inv), f2h(x[j * 4 + 1] * inv),
                              f2h(x[j * 4 + 2] * inv), f2h(x[j * 4 + 3] * inv));
    *(ushort4*)(p + lane * 4 + j * 256) = o4;
  }
}

extern "C" void kernel_launch(void* const* d_in, const int* in_sizes, int n_in,
                              void* d_out, int out_size, void* d_ws, size_t ws_size,
                              hipStream_t stream) {
  const float* query = (const float*)d_in[0];
  const float* mem = (const float*)d_in[1];
  const int* mask = (const int*)d_in[2];
  const float* Wm = (const float*)d_in[3];
  const float* bias = (const float*)d_in[4];
  float* out = (float*)d_out;   // fp32 output

  const long nQ = (long)B_ * SQL * DD;   // 16.7M
  const long nW = (long)DD * DD;
  const long nS = (long)B_ * SQL * SKL;

  char* ws = (char*)d_ws;
  u16* q16 = (u16*)ws; ws += nQ * 2;    // fp16(query); becomes P after proj+QK
  u16* memh = (u16*)ws; ws += nQ * 2;
  u16* memT = (u16*)ws; ws += nQ * 2;
  u16* q1 = (u16*)ws; ws += nQ * 2;     // projected q, fp16
  u16* wh = (u16*)ws; ws += nW * 2;
  u16* wl = (u16*)ws; ws += nW * 2;
  float* S = (float*)ws; ws += nS * 4;
  u16* P = q16;   // q16 dead after projection

  // fused1: cvt16(query) + split16(W)
  prep_k<<<2048 + 512, 256, 0, stream>>>(query, q16, Wm, wh, wl);
  // fused2: proj (blocks 0-511) + split_mem (blocks 512-4607), back-to-back
  proj_split_k<<<512 + 4096, 256, 0, stream>>>(q16, wh, wl, bias, q1, mem, memh, memT);
  // logits (1-term, 256x128): per batch 8x16 -> grid 1024
  gemm1_f16<0><<<1024, 256, 0, stream>>>(
      q1, memh, S, SKL, DD, 128,
      (long)SQL * DD, (long)SKL * DD, (long)SQL * SKL);
  // mask + softmax -> P fp16 (wave-per-row)
  softmax16_k<<<(B_ * SQL) / 4, 256, 0, stream>>>(S, mask, P);
  // PV (1-term, 256x128): per batch 8x8 -> grid 512
  gemm1_f16<0><<<512, 256, 0, stream>>>(
      P, memT, out, DD, SKL, 64,
      (long)SQL * SKL, (long)DD * SKL, (long)SQL * DD);
}

// Round 31
// 315.290 us; speedup vs baseline: 1.0525x; 1.0004x over previous
//
#include <hip/hip_runtime.h>

// FINAL (round 30): the triple-reproduced best configuration
// (R23/R25/R26/R28: 314.7/315.1/315.9us, absmax 0.0742 vs threshold 0.108).
// 11.5x over the correct naive fp32 baseline (3637us).
//
// Pipeline: q=query@W^T+b ; S=q@mem^T ; P=softmax(S+mask) ; out=P@mem
//  - prep_k:        fused fp32->fp16 convert(query) + hi/lo split(W)  [BW ceiling]
//  - proj_split_k:  proj 256x128 2-term fp16 (q16 x (Wh+Wl), fp32 acc)
//                   grid-fused back-to-back with mem split+transpose  [93us]
//  - gemm1_f16:     QK & PV, 1-term fp16, 256x128 tile, 4 waves, BK=64,
//                   XOR-swizzled LDS via pre-swizzled global source
//                   (global_load_lds dest linear, rule #21), batch-folded
//                   bijective XCD-chunk swizzle (FETCH at ideal)      [92/73us]
//  - softmax16_k:   wave-per-row, shfl-only, no LDS/barriers          [BW ceiling]
//
// Measured-null/negative at this structure (4 attempts): coarse dbuf (R10),
// depth-1 counted vmcnt (R18), 8-phase drain-0 (R24), 8-phase counted (R29)
// -- barrier cost x wave count dominates; the m201-class schedule needs its
// full co-designed body, not just the sync skeleton.
// Error budget: fp16 inputs + 1-term QK/PV + 2-term proj -> logit sigma ~1e-2,
// absmax 0.074 (1.46x margin). S stays fp32 (fp16 S would be ~0.10, too tight).

typedef __attribute__((ext_vector_type(8))) _Float16 f16x8;
typedef __attribute__((ext_vector_type(4))) float f32x4;
typedef unsigned short u16;
typedef unsigned int u32;

#define B_ 8
#define SQL 2048
#define SKL 2048
#define DD 1024
#define NEGC -1000000000.0f

static __device__ __forceinline__ u16 f2h(float x) {
  _Float16 h = (_Float16)x;                       // v_cvt_f16_f32, RNE
  return __builtin_bit_cast(u16, h);
}
static __device__ __forceinline__ float h2f(u16 v) {
  return (float)__builtin_bit_cast(_Float16, v);
}
static __device__ __forceinline__ void gload16(const void* g, void* l) {
  __builtin_amdgcn_global_load_lds((const __attribute__((address_space(1))) u32*)g,
                                   (__attribute__((address_space(3))) u32*)l, 16, 0, 0);
}

// ---------------- fused1: cvt16(query) [blocks 0..2047] + split16(W) [2048..2559] ----------------
__global__ __launch_bounds__(256) void prep_k(const float* __restrict__ query,
                                              u16* __restrict__ q16,
                                              const float* __restrict__ Wm,
                                              u16* __restrict__ wh, u16* __restrict__ wl) {
  if (blockIdx.x < 2048) {
    long n = (long)B_ * SQL * DD;
    long i = ((long)blockIdx.x * 256 + threadIdx.x) * 8;
    long stride = 2048L * 256 * 8;
    for (; i < n; i += stride) {
      float4 v0 = *(const float4*)(query + i);
      float4 v1 = *(const float4*)(query + i + 4);
      ushort4 o0 = make_ushort4(f2h(v0.x), f2h(v0.y), f2h(v0.z), f2h(v0.w));
      ushort4 o1 = make_ushort4(f2h(v1.x), f2h(v1.y), f2h(v1.z), f2h(v1.w));
      *(ushort4*)(q16 + i) = o0;
      *(ushort4*)(q16 + i + 4) = o1;
    }
  } else {
    long i = ((long)(blockIdx.x - 2048) * 256 + threadIdx.x) * 8;   // W: 1M elems
    float4 v0 = *(const float4*)(Wm + i);
    float4 v1 = *(const float4*)(Wm + i + 4);
    u16 h0 = f2h(v0.x), h1 = f2h(v0.y), h2 = f2h(v0.z), h3 = f2h(v0.w);
    u16 h4 = f2h(v1.x), h5 = f2h(v1.y), h6 = f2h(v1.z), h7 = f2h(v1.w);
    *(ushort4*)(wh + i) = make_ushort4(h0, h1, h2, h3);
    *(ushort4*)(wh + i + 4) = make_ushort4(h4, h5, h6, h7);
    *(ushort4*)(wl + i) = make_ushort4(f2h(v0.x - h2f(h0)), f2h(v0.y - h2f(h1)),
                                       f2h(v0.z - h2f(h2)), f2h(v0.w - h2f(h3)));
    *(ushort4*)(wl + i + 4) = make_ushort4(f2h(v1.x - h2f(h4)), f2h(v1.y - h2f(h5)),
                                           f2h(v1.z - h2f(h6)), f2h(v1.w - h2f(h7)));
  }
}

// ---------------- fused2: proj (256x128, TERMS=2) + split_mem (back-to-back) ----------------
// blocks [0,512): projection q16 @ (Wh+Wl)^T + bias -> q1 fp16
// blocks [512,4608): mem fp32 -> memh fp16 + memT fp16 [D][Sk]  (64x64 tiles)
__global__ __launch_bounds__(256, 2) void proj_split_k(
    const u16* __restrict__ Ah, const u16* __restrict__ Bh, const u16* __restrict__ Bl,
    const float* __restrict__ bias, u16* __restrict__ C0,
    const float* __restrict__ mem, u16* __restrict__ memh, u16* __restrict__ memT) {
  __shared__ u16 lA[256 * 64];     // 32KB (proj A; split_mem aliases 8.3KB of it)
  __shared__ u16 lB[128 * 128];    // 32KB (proj B dual)

  if (blockIdx.x < 512) {
    // ---- projection: TERMS=2 path, nwg=512 swizzle ----
    const int N = DD, K = DD;
    int id = blockIdx.x;
    int j = (id & 7) * 64 + (id >> 3);      // bijective, nwg=512
    const int TX = N >> 7;                  // 8
    const int by = j / TX, bx = j % TX;
    const int tid = threadIdx.x;
    const int l = tid & 63, w = tid >> 6;
    const int wr = w >> 1, wc = w & 1;
    const long am0 = (long)by * 256;
    const long bn0 = (long)bx * 128;

    f32x4 acc[8][4];
#pragma unroll
    for (int i = 0; i < 8; ++i)
#pragma unroll
      for (int j2 = 0; j2 < 4; ++j2) {
        f32x4 z = {0.f, 0.f, 0.f, 0.f};
        acc[i][j2] = z;
      }
    const int lrow = l & 15, lch = l >> 4;

    for (int k0 = 0; k0 < K; k0 += 64) {
      __syncthreads();
#pragma unroll
      for (int i = 0; i < 8; ++i) {
        int row = i * 32 + (tid >> 3);
        int cc = (tid & 7) ^ (row & 7);
        gload16(Ah + (am0 + row) * K + k0 + cc * 8, &lA[row * 64 + (tid & 7) * 8]);
      }
#pragma unroll
      for (int i = 0; i < 8; ++i) {
        int row = i * 16 + (tid >> 4);
        int s = tid & 15;
        int cc = s ^ (row & 15);
        const u16* src = (cc < 8) ? (Bh + (bn0 + row) * K + k0 + cc * 8)
                                  : (Bl + (bn0 + row) * K + k0 + (cc - 8) * 8);
        gload16(src, &lB[row * 128 + s * 8]);
      }
      __syncthreads();

#pragma unroll
      for (int kk = 0; kk < 2; ++kk) {
        f16x8 ah[8], bh[4], bl_[4];
#pragma unroll
        for (int f = 0; f < 8; ++f) {
          int ra = wr * 128 + f * 16 + lrow;
          int c = kk * 4 + lch;
          ah[f] = *(const f16x8*)&lA[ra * 64 + (c ^ (ra & 7)) * 8];
        }
#pragma unroll
        for (int f = 0; f < 4; ++f) {
          int rb = wc * 64 + f * 16 + lrow;
          int c = kk * 4 + lch;
          bh[f] = *(const f16x8*)&lB[rb * 128 + (c ^ (rb & 15)) * 8];
          bl_[f] = *(const f16x8*)&lB[rb * 128 + ((8 + c) ^ (rb & 15)) * 8];
        }
#pragma unroll
        for (int mf = 0; mf < 8; ++mf)
#pragma unroll
          for (int nf = 0; nf < 4; ++nf) {
            acc[mf][nf] = __builtin_amdgcn_mfma_f32_16x16x32_f16(ah[mf], bh[nf], acc[mf][nf], 0, 0, 0);
            acc[mf][nf] = __builtin_amdgcn_mfma_f32_16x16x32_f16(ah[mf], bl_[nf], acc[mf][nf], 0, 0, 0);
          }
      }
    }
#pragma unroll
    for (int mf = 0; mf < 8; ++mf)
#pragma unroll
      for (int nf = 0; nf < 4; ++nf)
#pragma unroll
        for (int r = 0; r < 4; ++r) {
          long row = am0 + wr * 128 + mf * 16 + (l >> 4) * 4 + r;
          long col = bn0 + wc * 64 + nf * 16 + (l & 15);
          C0[row * N + col] = f2h(acc[mf][nf][r] + bias[col]);
        }
  } else {
    // ---- split_mem: 64x64 transpose tiles, flattened grid (16,32,8) ----
    u16(*t)[65] = (u16(*)[65])lA;   // 64x65 u16 = 8.3KB, aliases lA
    int id2 = blockIdx.x - 512;
    int bx = id2 & 15, by = (id2 >> 4) & 31, bz = id2 >> 9;
    long bo = (long)bz * SKL * DD;
    int r0 = by * 64, c0 = bx * 64;
    int tr = threadIdx.x / 16, tc4 = (threadIdx.x % 16) * 4;
#pragma unroll
    for (int i = 0; i < 4; ++i) {
      int r = tr + i * 16;
      long idx = bo + (long)(r0 + r) * DD + c0 + tc4;
      float4 v = *(const float4*)(mem + idx);
      u16 h0 = f2h(v.x), h1 = f2h(v.y), h2 = f2h(v.z), h3 = f2h(v.w);
      *(ushort4*)(memh + idx) = make_ushort4(h0, h1, h2, h3);
      t[r][tc4 + 0] = h0; t[r][tc4 + 1] = h1; t[r][tc4 + 2] = h2; t[r][tc4 + 3] = h3;
    }
    __syncthreads();
#pragma unroll
    for (int i = 0; i < 4; ++i) {
      int c = tr + i * 16;   // output row = original column c0+c
      ushort4 v = make_ushort4(t[tc4 + 0][c], t[tc4 + 1][c], t[tc4 + 2][c], t[tc4 + 3][c]);
      *(ushort4*)(memT + bo + (long)(c0 + c) * SKL + r0 + tc4) = v;
    }
  }
}

// ---------------- TERMS=1 GEMM (QK / PV): 256x128, 4 waves, BK=64 ----------------
template <int OUTMODE>
__global__ __launch_bounds__(256, 2) void gemm1_f16(
    const u16* __restrict__ Ah, const u16* __restrict__ Bh,
    void* __restrict__ C0,
    int N, int K, int TPB, long batchA, long batchB, long batchC) {
  __shared__ u16 lA[256 * 64];
  __shared__ u16 lB[128 * 64];

  const int nwg = gridDim.x;
  int id = blockIdx.x;
  int j = (id & 7) * (nwg >> 3) + (id >> 3);
  const int TX = N >> 7;
  const int bz = j / TPB;
  const int r0_ = j % TPB;
  const int by = r0_ / TX, bx = r0_ % TX;

  const u16* pAh = Ah + (long)bz * batchA;
  const u16* pBh = Bh + (long)bz * batchB;

  const int tid = threadIdx.x;
  const int l = tid & 63, w = tid >> 6;
  const int wr = w >> 1, wc = w & 1;
  const long am0 = (long)by * 256;
  const long bn0 = (long)bx * 128;

  f32x4 acc[8][4];
#pragma unroll
  for (int i = 0; i < 8; ++i)
#pragma unroll
    for (int j2 = 0; j2 < 4; ++j2) {
      f32x4 z = {0.f, 0.f, 0.f, 0.f};
      acc[i][j2] = z;
    }
  const int lrow = l & 15, lch = l >> 4;

  for (int k0 = 0; k0 < K; k0 += 64) {
    __syncthreads();
#pragma unroll
    for (int i = 0; i < 8; ++i) {
      int row = i * 32 + (tid >> 3);
      int cc = (tid & 7) ^ (row & 7);
      gload16(pAh + (am0 + row) * K + k0 + cc * 8, &lA[row * 64 + (tid & 7) * 8]);
    }
#pragma unroll
    for (int i = 0; i < 4; ++i) {
      int row = i * 32 + (tid >> 3);
      int cc = (tid & 7) ^ (row & 7);
      gload16(pBh + (bn0 + row) * K + k0 + cc * 8, &lB[row * 64 + (tid & 7) * 8]);
    }
    __syncthreads();

#pragma unroll
    for (int kk = 0; kk < 2; ++kk) {
      f16x8 ah[8], bh[4];
#pragma unroll
      for (int f = 0; f < 8; ++f) {
        int ra = wr * 128 + f * 16 + lrow;
        int c = kk * 4 + lch;
        ah[f] = *(const f16x8*)&lA[ra * 64 + (c ^ (ra & 7)) * 8];
      }
#pragma unroll
      for (int f = 0; f < 4; ++f) {
        int rb = wc * 64 + f * 16 + lrow;
        int c = kk * 4 + lch;
        bh[f] = *(const f16x8*)&lB[rb * 64 + (c ^ (rb & 7)) * 8];
      }
#pragma unroll
      for (int mf = 0; mf < 8; ++mf)
#pragma unroll
        for (int nf = 0; nf < 4; ++nf)
          acc[mf][nf] = __builtin_amdgcn_mfma_f32_16x16x32_f16(ah[mf], bh[nf], acc[mf][nf], 0, 0, 0);
    }
  }

#pragma unroll
  for (int mf = 0; mf < 8; ++mf)
#pragma unroll
    for (int nf = 0; nf < 4; ++nf)
#pragma unroll
      for (int r = 0; r < 4; ++r) {
        long row = am0 + wr * 128 + mf * 16 + (l >> 4) * 4 + r;
        long col = bn0 + wc * 64 + nf * 16 + (l & 15);
        long idx = (long)bz * batchC + row * N + col;
        if (OUTMODE == 0) ((float*)C0)[idx] = acc[mf][nf][r];
        else              ((u16*)C0)[idx] = f2h(acc[mf][nf][r]);
      }
}

// ---------------- mask + row softmax, wave-per-row (no barriers/LDS) ----------------
__global__ __launch_bounds__(256) void softmax16_k(const float* __restrict__ S,
                                                   const int* __restrict__ M,
                                                   u16* __restrict__ P) {
  long row = (long)blockIdx.x * 4 + (threadIdx.x >> 6);
  const float* s = S + row * SKL;
  const int* m = M + row * SKL;
  u16* p = P + row * SKL;
  const int lane = threadIdx.x & 63;
  float x[32];
#pragma unroll
  for (int j = 0; j < 8; ++j) {
    float4 v = *(const float4*)(s + lane * 4 + j * 256);
    int4 q = *(const int4*)(m + lane * 4 + j * 256);
    x[j * 4 + 0] = q.x ? v.x : v.x + NEGC;
    x[j * 4 + 1] = q.y ? v.y : v.y + NEGC;
    x[j * 4 + 2] = q.z ? v.z : v.z + NEGC;
    x[j * 4 + 3] = q.w ? v.w : v.w + NEGC;
  }
  float mx = x[0];
#pragma unroll
  for (int j = 1; j < 32; ++j) mx = fmaxf(mx, x[j]);
#pragma unroll
  for (int o = 32; o >= 1; o >>= 1) mx = fmaxf(mx, __shfl_xor(mx, o, 64));
  float sum = 0.f;
#pragma unroll
  for (int j = 0; j < 32; ++j) { x[j] = __expf(x[j] - mx); sum += x[j]; }
#pragma unroll
  for (int o = 32; o >= 1; o >>= 1) sum += __shfl_xor(sum, o, 64);
  float inv = 1.f / sum;
#pragma unroll
  for (int j = 0; j < 8; ++j) {
    ushort4 o4 = make_ushort4(f2h(x[j * 4 + 0] * inv), f2h(x[j * 4 + 1] * inv),
                              f2h(x[j * 4 + 2] * inv), f2h(x[j * 4 + 3] * inv));
    *(ushort4*)(p + lane * 4 + j * 256) = o4;
  }
}

extern "C" void kernel_launch(void* const* d_in, const int* in_sizes, int n_in,
                              void* d_out, int out_size, void* d_ws, size_t ws_size,
                              hipStream_t stream) {
  const float* query = (const float*)d_in[0];
  const float* mem = (const float*)d_in[1];
  const int* mask = (const int*)d_in[2];
  const float* Wm = (const float*)d_in[3];
  const float* bias = (const float*)d_in[4];
  float* out = (float*)d_out;   // fp32 output

  const long nQ = (long)B_ * SQL * DD;   // 16.7M
  const long nW = (long)DD * DD;
  const long nS = (long)B_ * SQL * SKL;

  char* ws = (char*)d_ws;
  u16* q16 = (u16*)ws; ws += nQ * 2;    // fp16(query); becomes P after proj+QK
  u16* memh = (u16*)ws; ws += nQ * 2;
  u16* memT = (u16*)ws; ws += nQ * 2;
  u16* q1 = (u16*)ws; ws += nQ * 2;     // projected q, fp16
  u16* wh = (u16*)ws; ws += nW * 2;
  u16* wl = (u16*)ws; ws += nW * 2;
  float* S = (float*)ws; ws += nS * 4;
  u16* P = q16;   // q16 dead after projection

  // fused1: cvt16(query) + split16(W)
  prep_k<<<2048 + 512, 256, 0, stream>>>(query, q16, Wm, wh, wl);
  // fused2: proj (blocks 0-511) + split_mem (blocks 512-4607), back-to-back
  proj_split_k<<<512 + 4096, 256, 0, stream>>>(q16, wh, wl, bias, q1, mem, memh, memT);
  // logits (1-term, 256x128): per batch 8x16 -> grid 1024
  gemm1_f16<0><<<1024, 256, 0, stream>>>(
      q1, memh, S, SKL, DD, 128,
      (long)SQL * DD, (long)SKL * DD, (long)SQL * SKL);
  // mask + softmax -> P fp16 (wave-per-row)
  softmax16_k<<<(B_ * SQL) / 4, 256, 0, stream>>>(S, mask, P);
  // PV (1-term, 256x128): per batch 8x8 -> grid 512
  gemm1_f16<0><<<512, 256, 0, stream>>>(
      P, memT, out, DD, SKL, 64,
      (long)SQL * SKL, (long)DD * SKL, (long)SQL * DD);
}